// Round 1
// baseline (366.434 us; speedup 1.0000x reference)
//
#include <hip/hip_runtime.h>

// GRU: B=8192 chains, T=512 steps, IN=5, H=7, fused heads.
// Layout: 8 lanes per batch element (lane j = hidden unit j, j=7 idle-ish).
// h replicated per-lane (7 regs); per-step: 21 FMA hidden matvec (local),
// 15 FMA input proj, 3 fused sigmoid/tanh, 7-shfl gather of h_new, 7 FMA head.
// 256 thr/block x 256 blocks = 65536 threads = 1 wave/SIMD machine-wide.

namespace {
constexpr int Bn = 8192;
constexpr int Tn = 512;
constexpr int INn = 5;
constexpr int Hn = 7;
constexpr long long OFF_OR = (long long)Bn * Tn * 3;             // 12582912
constexpr long long OFF_HL = OFF_OR + (long long)Bn * Tn;        // 16777216
constexpr float LOG2E = 1.44269504088896340736f;
}

__device__ __forceinline__ float fast_sigmoid(float x) {
    // 1 / (1 + 2^(-x*log2e))
    float e = __builtin_amdgcn_exp2f(-LOG2E * x);
    return __builtin_amdgcn_rcpf(1.0f + e);
}

__device__ __forceinline__ float fast_tanh(float x) {
    // 2 / (1 + 2^(-2x*log2e)) - 1
    float e = __builtin_amdgcn_exp2f(-2.0f * LOG2E * x);
    return __builtin_amdgcn_rcpf(1.0f + e) * 2.0f - 1.0f;
}

__global__ __launch_bounds__(256, 1) void gru_fused_kernel(
    const float* __restrict__ x,     // [B, T, IN]
    const float* __restrict__ W_ih,  // [21, 5]
    const float* __restrict__ W_hh,  // [21, 7]
    const float* __restrict__ b_ih,  // [21]
    const float* __restrict__ b_hh,  // [21]
    const float* __restrict__ W_h0,  // [7, 1]
    const float* __restrict__ W_m,   // [3, 7]
    const float* __restrict__ b_m,   // [3]
    const float* __restrict__ W_r,   // [1, 7]
    const float* __restrict__ b_r,   // [1]
    float* __restrict__ out)
{
    const int tid  = threadIdx.x;
    const int lane = tid & 63;
    const int j    = tid & 7;            // hidden-unit slot (7 = pad)
    const int grp  = tid >> 3;           // group within block (0..31)
    const int b    = blockIdx.x * 32 + grp;
    const int jj   = (j < 7) ? j : 6;    // clamp pad lane's weight loads
    const int base_lane = lane & ~7;     // first lane of my 8-lane group

    // ---- per-lane weights (registers) ----
    float wih_r[INn], wih_z[INn], wih_n[INn];
    #pragma unroll
    for (int i = 0; i < INn; ++i) {
        wih_r[i] = W_ih[jj * INn + i];
        wih_z[i] = W_ih[(Hn + jj) * INn + i];
        wih_n[i] = W_ih[(2 * Hn + jj) * INn + i];
    }
    float whh_r[Hn], whh_z[Hn], whh_n[Hn];
    #pragma unroll
    for (int k = 0; k < Hn; ++k) {
        whh_r[k] = W_hh[jj * Hn + k];
        whh_z[k] = W_hh[(Hn + jj) * Hn + k];
        whh_n[k] = W_hh[(2 * Hn + jj) * Hn + k];
    }
    const float bir = b_ih[jj], biz = b_ih[Hn + jj], bin_ = b_ih[2 * Hn + jj];
    const float bhr = b_hh[jj], bhz = b_hh[Hn + jj], bhn = b_hh[2 * Hn + jj];

    // head weights: lanes 0..2 -> W_m rows, lane 3 -> W_r, lanes 4..7 -> zero
    float whead[Hn];
    float bhead = 0.0f;
    #pragma unroll
    for (int k = 0; k < Hn; ++k) whead[k] = 0.0f;
    if (j < 3) {
        #pragma unroll
        for (int k = 0; k < Hn; ++k) whead[k] = W_m[j * Hn + k];
        bhead = b_m[j];
    } else if (j == 3) {
        #pragma unroll
        for (int k = 0; k < Hn; ++k) whead[k] = W_r[k];
        bhead = b_r[0];
    }

    // ---- replicated hidden state ----
    float h[Hn];
    #pragma unroll
    for (int k = 0; k < Hn; ++k) h[k] = W_h0[k];   // h0 broadcast of W_h0[:,0]

    const float* xp  = x + (long long)b * (Tn * INn);
    float* om  = out + (long long)b * (Tn * 3);
    float* orr = out + OFF_OR + (long long)b * Tn;

    // prime x for t=0
    float xc[INn];
    #pragma unroll
    for (int i = 0; i < INn; ++i) xc[i] = xp[i];

    for (int t = 0; t < Tn; ++t) {
        // prefetch x for t+1 (clamped)
        float xnx[INn];
        const float* xnp = xp + (long long)((t + 1 < Tn) ? (t + 1) : t) * INn;
        #pragma unroll
        for (int i = 0; i < INn; ++i) xnx[i] = xnp[i];

        // hidden matvec (local, replicated h)
        float gr = bhr, gz = bhz, gn = bhn;
        #pragma unroll
        for (int k = 0; k < Hn; ++k) {
            gr = fmaf(whh_r[k], h[k], gr);
            gz = fmaf(whh_z[k], h[k], gz);
            gn = fmaf(whh_n[k], h[k], gn);
        }
        // input projection
        float xr = bir, xz = biz, xn = bin_;
        #pragma unroll
        for (int i = 0; i < INn; ++i) {
            xr = fmaf(wih_r[i], xc[i], xr);
            xz = fmaf(wih_z[i], xc[i], xz);
            xn = fmaf(wih_n[i], xc[i], xn);
        }
        // gates
        float r = fast_sigmoid(xr + gr);
        float z = fast_sigmoid(xz + gz);
        float n = fast_tanh(xn + r * gn);
        float hj = h[jj];
        float hnew = n + z * (hj - n);   // (1-z)*n + z*h

        // gather h_new across the 8-lane group -> replicated h
        #pragma unroll
        for (int k = 0; k < Hn; ++k)
            h[k] = __shfl(hnew, base_lane + k);

        // heads (lane-private weights; only lanes 0..3 store)
        float acc = bhead;
        #pragma unroll
        for (int k = 0; k < Hn; ++k) acc = fmaf(whead[k], h[k], acc);
        if (j < 3) {
            om[t * 3 + j] = acc;
        } else if (j == 3) {
            orr[t] = acc;
        }

        #pragma unroll
        for (int i = 0; i < INn; ++i) xc[i] = xnx[i];
    }

    // h_last: [1, B, H]
    if (j < Hn) out[OFF_HL + (long long)b * Hn + j] = h[j];
}

extern "C" void kernel_launch(void* const* d_in, const int* in_sizes, int n_in,
                              void* d_out, int out_size, void* d_ws, size_t ws_size,
                              hipStream_t stream) {
    const float* x    = (const float*)d_in[0];
    // d_in[1] = batch_size (scalar), unused — B compiled in
    const float* W_ih = (const float*)d_in[2];
    const float* W_hh = (const float*)d_in[3];
    const float* b_ih = (const float*)d_in[4];
    const float* b_hh = (const float*)d_in[5];
    const float* W_h0 = (const float*)d_in[6];
    const float* W_m  = (const float*)d_in[7];
    const float* b_m  = (const float*)d_in[8];
    const float* W_r  = (const float*)d_in[9];
    const float* b_r  = (const float*)d_in[10];
    float* out = (float*)d_out;

    dim3 grid(Bn / 32);   // 256 blocks
    dim3 block(256);      // 32 batch elements x 8 lanes
    gru_fused_kernel<<<grid, block, 0, stream>>>(x, W_ih, W_hh, b_ih, b_hh,
                                                 W_h0, W_m, b_m, W_r, b_r, out);
}

// Round 2
// 293.423 us; speedup vs baseline: 1.2488x; 1.2488x over previous
//
#include <hip/hip_runtime.h>

// GRU: B=8192 chains, T=512 steps, IN=5, H=7, fused heads.
// R2: x staged through double-buffered LDS in 32-step tiles to remove the
// per-step global-load latency (R1 was ~1190 cyc/step, ~1000 of it exposed
// L2/L3 load latency with 1 wave/SIMD and no TLP to hide it).
// Layout: 8 lanes per batch element (lane j = hidden unit j, j=7 pad).
// h replicated per-lane; per-step: 21 FMA hidden matvec (local), 15 FMA input
// proj, 3 fused sigmoid/tanh (exp2+rcp), 7-bpermute gather, 7 FMA heads.
// 256 thr/block x 256 blocks = 65536 threads = 1 wave/SIMD machine-wide.

namespace {
constexpr int Bn = 8192;
constexpr int Tn = 512;
constexpr int INn = 5;
constexpr int Hn = 7;
constexpr int TILE = 32;                 // steps per LDS tile
constexpr int NTILE = Tn / TILE;         // 16
constexpr int BPB = 32;                  // batches per block
constexpr int XSTR = 164;                // padded floats/batch in LDS (160+4):
                                         // bank(g*164+c) = (4g+c)%32 -> groups
                                         // 0..7 hit distinct banks per read
constexpr long long OFF_OR = (long long)Bn * Tn * 3;       // out_r offset
constexpr long long OFF_HL = OFF_OR + (long long)Bn * Tn;  // h_last offset
constexpr float LOG2E = 1.44269504088896340736f;
}

__device__ __forceinline__ float fast_sigmoid(float x) {
    float e = __builtin_amdgcn_exp2f(-LOG2E * x);
    return __builtin_amdgcn_rcpf(1.0f + e);
}

__device__ __forceinline__ float fast_tanh(float x) {
    float e = __builtin_amdgcn_exp2f(-2.0f * LOG2E * x);
    return __builtin_amdgcn_rcpf(1.0f + e) * 2.0f - 1.0f;
}

__global__ __launch_bounds__(256, 1) void gru_fused_kernel(
    const float* __restrict__ x,     // [B, T, IN]
    const float* __restrict__ W_ih,  // [21, 5]
    const float* __restrict__ W_hh,  // [21, 7]
    const float* __restrict__ b_ih,  // [21]
    const float* __restrict__ b_hh,  // [21]
    const float* __restrict__ W_h0,  // [7, 1]
    const float* __restrict__ W_m,   // [3, 7]
    const float* __restrict__ b_m,   // [3]
    const float* __restrict__ W_r,   // [1, 7]
    const float* __restrict__ b_r,   // [1]
    float* __restrict__ out)
{
    __shared__ float lds_x[2][BPB * XSTR];   // 2 x 20.5 KB

    const int tid  = threadIdx.x;
    const int lane = tid & 63;
    const int j    = tid & 7;            // hidden-unit slot (7 = pad)
    const int g    = tid >> 3;           // batch slot in block (0..31)
    const int b    = blockIdx.x * BPB + g;
    const int jj   = (j < 7) ? j : 6;    // clamp pad lane's weight loads
    const int base_lane = lane & ~7;     // first lane of my 8-lane group

    // ---- per-lane weights (registers) ----
    float wih_r[INn], wih_z[INn], wih_n[INn];
    #pragma unroll
    for (int i = 0; i < INn; ++i) {
        wih_r[i] = W_ih[jj * INn + i];
        wih_z[i] = W_ih[(Hn + jj) * INn + i];
        wih_n[i] = W_ih[(2 * Hn + jj) * INn + i];
    }
    float whh_r[Hn], whh_z[Hn], whh_n[Hn];
    #pragma unroll
    for (int k = 0; k < Hn; ++k) {
        whh_r[k] = W_hh[jj * Hn + k];
        whh_z[k] = W_hh[(Hn + jj) * Hn + k];
        whh_n[k] = W_hh[(2 * Hn + jj) * Hn + k];
    }
    const float bir = b_ih[jj], biz = b_ih[Hn + jj], bin_ = b_ih[2 * Hn + jj];
    const float bhr = b_hh[jj], bhz = b_hh[Hn + jj], bhn = b_hh[2 * Hn + jj];

    // head weights: lanes 0..2 -> W_m rows, lane 3 -> W_r, lanes 4..7 -> zero
    float whead[Hn];
    float bhead = 0.0f;
    #pragma unroll
    for (int k = 0; k < Hn; ++k) whead[k] = 0.0f;
    if (j < 3) {
        #pragma unroll
        for (int k = 0; k < Hn; ++k) whead[k] = W_m[j * Hn + k];
        bhead = b_m[j];
    } else if (j == 3) {
        #pragma unroll
        for (int k = 0; k < Hn; ++k) whead[k] = W_r[k];
        bhead = b_r[0];
    }

    // ---- replicated hidden state ----
    float h[Hn];
    #pragma unroll
    for (int k = 0; k < Hn; ++k) h[k] = W_h0[k];

    const float* xb  = x + (long long)b * (Tn * INn);   // 2560 floats, 16B-aligned
    float* om  = out + (long long)b * (Tn * 3);
    float* orr = out + OFF_OR + (long long)b * Tn;

    // ---- prologue: load tile 0 into staging registers ----
    // per batch-tile: 160 floats = 40 float4; lane j takes float4 #(j + 8i)
    float4 stage[5];
    #pragma unroll
    for (int i = 0; i < 5; ++i)
        stage[i] = *(const float4*)(xb + (j * 4 + i * 32));

    int cur = 0;
    for (int tl = 0; tl < NTILE; ++tl) {
        // commit staged tile to LDS
        #pragma unroll
        for (int i = 0; i < 5; ++i)
            *(float4*)&lds_x[cur][g * XSTR + j * 4 + i * 32] = stage[i];
        __syncthreads();

        // prefetch next tile from global (consumed in 32 steps -> latency hidden)
        if (tl + 1 < NTILE) {
            const float* src = xb + (tl + 1) * (TILE * INn);
            #pragma unroll
            for (int i = 0; i < 5; ++i)
                stage[i] = *(const float4*)(src + (j * 4 + i * 32));
        }

        const float* xl = &lds_x[cur][g * XSTR];

        // prime step-0 x from LDS
        float xc[INn];
        #pragma unroll
        for (int i = 0; i < INn; ++i) xc[i] = xl[i];

        #pragma unroll 4
        for (int tt = 0; tt < TILE; ++tt) {
            const int t = tl * TILE + tt;

            // prefetch next step's x from LDS (clamped; tt=31 re-reads self)
            const int tn = (tt + 1 < TILE) ? (tt + 1) : tt;
            float xnx[INn];
            #pragma unroll
            for (int i = 0; i < INn; ++i) xnx[i] = xl[tn * INn + i];

            // hidden matvec (local, replicated h)
            float gr = bhr, gz = bhz, gn = bhn;
            #pragma unroll
            for (int k = 0; k < Hn; ++k) {
                gr = fmaf(whh_r[k], h[k], gr);
                gz = fmaf(whh_z[k], h[k], gz);
                gn = fmaf(whh_n[k], h[k], gn);
            }
            // input projection
            float xr = bir, xz = biz, xn = bin_;
            #pragma unroll
            for (int i = 0; i < INn; ++i) {
                xr = fmaf(wih_r[i], xc[i], xr);
                xz = fmaf(wih_z[i], xc[i], xz);
                xn = fmaf(wih_n[i], xc[i], xn);
            }
            // gates
            float r = fast_sigmoid(xr + gr);
            float z = fast_sigmoid(xz + gz);
            float n = fast_tanh(xn + r * gn);
            float hj = h[jj];
            float hnew = n + z * (hj - n);   // (1-z)*n + z*h

            // gather h_new across the 8-lane group -> replicated h
            #pragma unroll
            for (int k = 0; k < Hn; ++k)
                h[k] = __shfl(hnew, base_lane + k);

            // heads (lane-private weights; only lanes 0..3 store)
            float acc = bhead;
            #pragma unroll
            for (int k = 0; k < Hn; ++k) acc = fmaf(whead[k], h[k], acc);
            if (j < 3) {
                om[t * 3 + j] = acc;
            } else if (j == 3) {
                orr[t] = acc;
            }

            #pragma unroll
            for (int i = 0; i < INn; ++i) xc[i] = xnx[i];
        }
        cur ^= 1;
    }

    // h_last: [1, B, H]
    if (j < Hn) out[OFF_HL + (long long)b * Hn + j] = h[j];
}

extern "C" void kernel_launch(void* const* d_in, const int* in_sizes, int n_in,
                              void* d_out, int out_size, void* d_ws, size_t ws_size,
                              hipStream_t stream) {
    const float* x    = (const float*)d_in[0];
    // d_in[1] = batch_size (scalar), unused — B compiled in
    const float* W_ih = (const float*)d_in[2];
    const float* W_hh = (const float*)d_in[3];
    const float* b_ih = (const float*)d_in[4];
    const float* b_hh = (const float*)d_in[5];
    const float* W_h0 = (const float*)d_in[6];
    const float* W_m  = (const float*)d_in[7];
    const float* b_m  = (const float*)d_in[8];
    const float* W_r  = (const float*)d_in[9];
    const float* b_r  = (const float*)d_in[10];
    float* out = (float*)d_out;

    dim3 grid(Bn / BPB);  // 256 blocks
    dim3 block(256);      // 32 batch elements x 8 lanes
    gru_fused_kernel<<<grid, block, 0, stream>>>(x, W_ih, W_hh, b_ih, b_hh,
                                                 W_h0, W_m, b_m, W_r, b_r, out);
}

// Round 3
// 283.710 us; speedup vs baseline: 1.2916x; 1.0342x over previous
//
#include <hip/hip_runtime.h>

// GRU: B=8192 chains, T=512 steps, IN=5, H=7, fused heads.
// R3: h-gather via DPP (VALU pipe, ~6 cyc chain) instead of ds_bpermute
// (LDS pipe, ~120+ cyc on the critical path every step). R2 post-mortem:
// 863 cyc/step, ~290 issue, ~520 stall = bpermute latency with 1 wave/SIMD.
// Layout: 8 lanes per batch element (lane j = hidden unit j, j=7 pad).
// h replicated per-lane; per-step: 21 FMA hidden matvec (local), 15 FMA input
// proj, 3 fused sigmoid/tanh (exp2+rcp), 18-op DPP gather, 7 FMA heads.
// 256 thr/block x 256 blocks = 65536 threads = 1 wave/SIMD machine-wide.

namespace {
constexpr int Bn = 8192;
constexpr int Tn = 512;
constexpr int INn = 5;
constexpr int Hn = 7;
constexpr int TILE = 32;                 // steps per LDS tile
constexpr int NTILE = Tn / TILE;         // 16
constexpr int BPB = 32;                  // batches per block
constexpr int XSTR = 164;                // padded floats/batch in LDS:
                                         // bank(g*164+c) = (4g+c)%32 -> the 8
                                         // groups of a wave hit distinct banks
constexpr long long OFF_OR = (long long)Bn * Tn * 3;       // out_r offset
constexpr long long OFF_HL = OFF_OR + (long long)Bn * Tn;  // h_last offset
constexpr float LOG2E = 1.44269504088896340736f;
}

__device__ __forceinline__ float fast_sigmoid(float x) {
    float e = __builtin_amdgcn_exp2f(-LOG2E * x);
    return __builtin_amdgcn_rcpf(1.0f + e);
}

__device__ __forceinline__ float fast_tanh(float x) {
    float e = __builtin_amdgcn_exp2f(-2.0f * LOG2E * x);
    return __builtin_amdgcn_rcpf(1.0f + e) * 2.0f - 1.0f;
}

// DPP move: returns src shuffled by CTRL; out-of-bounds lanes -> 0 (bound_ctrl),
// always overridden by the cndmask select below.
template<int CTRL>
__device__ __forceinline__ float dppf(float v) {
    int r = __builtin_amdgcn_update_dpp(0, __builtin_bit_cast(int, v),
                                        CTRL, 0xF, 0xF, true);
    return __builtin_bit_cast(float, r);
}

// Broadcast hnew(lane base+k) -> h[k] for all 8 lanes of each aligned 8-group.
// quad_perm[k,k,k,k] gives every quad its own lane-k value; row_shr:4 copies
// low-quad values to the high quad of the same 8-group, row_shl:4 the reverse.
// lo = ((tid & 4) == 0): lane is in the low quad of its 8-group.
__device__ __forceinline__ void gather_h(float hnew, bool lo, float h[Hn]) {
    float q0 = dppf<0x00>(hnew);   // quad_perm [0,0,0,0]
    float q1 = dppf<0x55>(hnew);   // quad_perm [1,1,1,1]
    float q2 = dppf<0xAA>(hnew);   // quad_perm [2,2,2,2]
    float q3 = dppf<0xFF>(hnew);   // quad_perm [3,3,3,3]
    float r0 = dppf<0x114>(q0);    // row_shr:4
    float r1 = dppf<0x114>(q1);
    float r2 = dppf<0x114>(q2);
    float r3 = dppf<0x114>(q3);
    float l0 = dppf<0x104>(q0);    // row_shl:4
    float l1 = dppf<0x104>(q1);
    float l2 = dppf<0x104>(q2);
    h[0] = lo ? q0 : r0;
    h[1] = lo ? q1 : r1;
    h[2] = lo ? q2 : r2;
    h[3] = lo ? q3 : r3;
    h[4] = lo ? l0 : q0;
    h[5] = lo ? l1 : q1;
    h[6] = lo ? l2 : q2;
}

__global__ __launch_bounds__(256, 1) void gru_fused_kernel(
    const float* __restrict__ x,     // [B, T, IN]
    const float* __restrict__ W_ih,  // [21, 5]
    const float* __restrict__ W_hh,  // [21, 7]
    const float* __restrict__ b_ih,  // [21]
    const float* __restrict__ b_hh,  // [21]
    const float* __restrict__ W_h0,  // [7, 1]
    const float* __restrict__ W_m,   // [3, 7]
    const float* __restrict__ b_m,   // [3]
    const float* __restrict__ W_r,   // [1, 7]
    const float* __restrict__ b_r,   // [1]
    float* __restrict__ out)
{
    __shared__ float lds_x[2][BPB * XSTR];   // 2 x 20.5 KB

    const int tid  = threadIdx.x;
    const int j    = tid & 7;            // hidden-unit slot (7 = pad)
    const int g    = tid >> 3;           // batch slot in block (0..31)
    const int b    = blockIdx.x * BPB + g;
    const int jj   = (j < 7) ? j : 6;    // clamp pad lane's weight loads
    const bool lo  = ((tid & 4) == 0);   // low quad of my 8-lane group

    // ---- per-lane weights (registers) ----
    float wih_r[INn], wih_z[INn], wih_n[INn];
    #pragma unroll
    for (int i = 0; i < INn; ++i) {
        wih_r[i] = W_ih[jj * INn + i];
        wih_z[i] = W_ih[(Hn + jj) * INn + i];
        wih_n[i] = W_ih[(2 * Hn + jj) * INn + i];
    }
    float whh_r[Hn], whh_z[Hn], whh_n[Hn];
    #pragma unroll
    for (int k = 0; k < Hn; ++k) {
        whh_r[k] = W_hh[jj * Hn + k];
        whh_z[k] = W_hh[(Hn + jj) * Hn + k];
        whh_n[k] = W_hh[(2 * Hn + jj) * Hn + k];
    }
    const float bir = b_ih[jj], biz = b_ih[Hn + jj], bin_ = b_ih[2 * Hn + jj];
    const float bhr = b_hh[jj], bhz = b_hh[Hn + jj], bhn = b_hh[2 * Hn + jj];

    // head weights: lanes 0..2 -> W_m rows, lane 3 -> W_r, lanes 4..7 -> zero
    float whead[Hn];
    float bhead = 0.0f;
    #pragma unroll
    for (int k = 0; k < Hn; ++k) whead[k] = 0.0f;
    if (j < 3) {
        #pragma unroll
        for (int k = 0; k < Hn; ++k) whead[k] = W_m[j * Hn + k];
        bhead = b_m[j];
    } else if (j == 3) {
        #pragma unroll
        for (int k = 0; k < Hn; ++k) whead[k] = W_r[k];
        bhead = b_r[0];
    }

    // ---- replicated hidden state ----
    float h[Hn];
    #pragma unroll
    for (int k = 0; k < Hn; ++k) h[k] = W_h0[k];

    const float* xb  = x + (long long)b * (Tn * INn);
    float* om  = out + (long long)b * (Tn * 3);
    float* orr = out + OFF_OR + (long long)b * Tn;

    // ---- prologue: load tile 0 into staging registers ----
    // per batch-tile: 160 floats = 40 float4; lane j takes float4 #(j + 8i)
    float4 stage[5];
    #pragma unroll
    for (int i = 0; i < 5; ++i)
        stage[i] = *(const float4*)(xb + (j * 4 + i * 32));

    int cur = 0;
    for (int tl = 0; tl < NTILE; ++tl) {
        // commit staged tile to LDS
        #pragma unroll
        for (int i = 0; i < 5; ++i)
            *(float4*)&lds_x[cur][g * XSTR + j * 4 + i * 32] = stage[i];
        __syncthreads();

        // prefetch next tile from global (consumed in 32 steps -> hidden)
        if (tl + 1 < NTILE) {
            const float* src = xb + (tl + 1) * (TILE * INn);
            #pragma unroll
            for (int i = 0; i < 5; ++i)
                stage[i] = *(const float4*)(src + (j * 4 + i * 32));
        }

        const float* xl = &lds_x[cur][g * XSTR];

        // prime step-0 x from LDS
        float xc[INn];
        #pragma unroll
        for (int i = 0; i < INn; ++i) xc[i] = xl[i];

        #pragma unroll 4
        for (int tt = 0; tt < TILE; ++tt) {
            const int t = tl * TILE + tt;

            // prefetch next step's x from LDS (clamped; tt=31 re-reads self)
            const int tn = (tt + 1 < TILE) ? (tt + 1) : tt;
            float xnx[INn];
            #pragma unroll
            for (int i = 0; i < INn; ++i) xnx[i] = xl[tn * INn + i];

            // hidden matvec (local, replicated h)
            float gr = bhr, gz = bhz, gn = bhn;
            #pragma unroll
            for (int k = 0; k < Hn; ++k) {
                gr = fmaf(whh_r[k], h[k], gr);
                gz = fmaf(whh_z[k], h[k], gz);
                gn = fmaf(whh_n[k], h[k], gn);
            }
            // input projection
            float xr = bir, xz = biz, xn = bin_;
            #pragma unroll
            for (int i = 0; i < INn; ++i) {
                xr = fmaf(wih_r[i], xc[i], xr);
                xz = fmaf(wih_z[i], xc[i], xz);
                xn = fmaf(wih_n[i], xc[i], xn);
            }
            // gates
            float r = fast_sigmoid(xr + gr);
            float z = fast_sigmoid(xz + gz);
            float n = fast_tanh(xn + r * gn);
            float hj = h[jj];
            float hnew = n + z * (hj - n);   // (1-z)*n + z*h

            // gather h_new across the 8-lane group -> replicated h (VALU DPP)
            gather_h(hnew, lo, h);

            // heads (lane-private weights; only lanes 0..3 store)
            float acc = bhead;
            #pragma unroll
            for (int k = 0; k < Hn; ++k) acc = fmaf(whead[k], h[k], acc);
            if (j < 3) {
                om[t * 3 + j] = acc;
            } else if (j == 3) {
                orr[t] = acc;
            }

            #pragma unroll
            for (int i = 0; i < INn; ++i) xc[i] = xnx[i];
        }
        cur ^= 1;
    }

    // h_last: [1, B, H]
    if (j < Hn) out[OFF_HL + (long long)b * Hn + j] = h[j];
}

extern "C" void kernel_launch(void* const* d_in, const int* in_sizes, int n_in,
                              void* d_out, int out_size, void* d_ws, size_t ws_size,
                              hipStream_t stream) {
    const float* x    = (const float*)d_in[0];
    // d_in[1] = batch_size (scalar), unused — B compiled in
    const float* W_ih = (const float*)d_in[2];
    const float* W_hh = (const float*)d_in[3];
    const float* b_ih = (const float*)d_in[4];
    const float* b_hh = (const float*)d_in[5];
    const float* W_h0 = (const float*)d_in[6];
    const float* W_m  = (const float*)d_in[7];
    const float* b_m  = (const float*)d_in[8];
    const float* W_r  = (const float*)d_in[9];
    const float* b_r  = (const float*)d_in[10];
    float* out = (float*)d_out;

    dim3 grid(Bn / BPB);  // 256 blocks
    dim3 block(256);      // 32 batch elements x 8 lanes
    gru_fused_kernel<<<grid, block, 0, stream>>>(x, W_ih, W_hh, b_ih, b_hh,
                                                 W_h0, W_m, b_m, W_r, b_r, out);
}

// Round 4
// 277.087 us; speedup vs baseline: 1.3224x; 1.0239x over previous
//
#include <hip/hip_runtime.h>

// GRU: B=8192 chains, T=512 steps, IN=5, H=7, fused heads.
// R4: 16 lanes/batch -> 131072 threads = 2048 waves = 2 waves/SIMD.
// R3 post-mortem: 816 cyc/step at 1 wave/SIMD, ~50% dependency-stall (CPI~4
// on chained VALU with zero TLP). Fix = second co-resident wave, not shorter
// chains. Work split by DATA (uniform code): lane l (j=l&7): slot0 = r_j row
// (lanes 0-7) / z_j row (lanes 8-15); slot1 = n_j row on BOTH halves.
// One sigmoid/lane -> r (lo) / z (hi); row_ror:8 swaps; all lanes compute
// tanh + hnew (valid everywhere, period-8) -> R3's verified 18-op DPP gather.
// 4 transcendentals/lane (was 6). 256 thr x 512 blocks.

namespace {
constexpr int Bn = 8192;
constexpr int Tn = 512;
constexpr int INn = 5;
constexpr int Hn = 7;
constexpr int TILE = 32;                 // steps per LDS tile
constexpr int NTILE = Tn / TILE;         // 16
constexpr int BPB = 16;                  // batches per block (256 thr / 16)
constexpr int XSTR = 164;                // padded floats/batch in LDS:
                                         // 4 groups/wave at banks 4g apart
constexpr long long OFF_OR = (long long)Bn * Tn * 3;       // out_r offset
constexpr long long OFF_HL = OFF_OR + (long long)Bn * Tn;  // h_last offset
constexpr float LOG2E = 1.44269504088896340736f;
}

__device__ __forceinline__ float fast_sigmoid(float x) {
    float e = __builtin_amdgcn_exp2f(-LOG2E * x);
    return __builtin_amdgcn_rcpf(1.0f + e);
}

__device__ __forceinline__ float fast_tanh(float x) {
    float e = __builtin_amdgcn_exp2f(-2.0f * LOG2E * x);
    return __builtin_amdgcn_rcpf(1.0f + e) * 2.0f - 1.0f;
}

template<int CTRL>
__device__ __forceinline__ float dppf(float v) {
    int r = __builtin_amdgcn_update_dpp(0, __builtin_bit_cast(int, v),
                                        CTRL, 0xF, 0xF, true);
    return __builtin_bit_cast(float, r);
}

// Replicate hnew (lane base+k of each aligned 8-group holds h_k, k=0..6,
// pattern period-8 across the wave) into h[0..6] on every lane.
// Verified in R3. Never reads lanes 7/15 mod 16.
__device__ __forceinline__ void gather_h(float hnew, bool lo, float h[Hn]) {
    float q0 = dppf<0x00>(hnew);   // quad_perm [0,0,0,0]
    float q1 = dppf<0x55>(hnew);   // quad_perm [1,1,1,1]
    float q2 = dppf<0xAA>(hnew);   // quad_perm [2,2,2,2]
    float q3 = dppf<0xFF>(hnew);   // quad_perm [3,3,3,3]
    float r0 = dppf<0x114>(q0);    // row_shr:4
    float r1 = dppf<0x114>(q1);
    float r2 = dppf<0x114>(q2);
    float r3 = dppf<0x114>(q3);
    float l0 = dppf<0x104>(q0);    // row_shl:4
    float l1 = dppf<0x104>(q1);
    float l2 = dppf<0x104>(q2);
    h[0] = lo ? q0 : r0;
    h[1] = lo ? q1 : r1;
    h[2] = lo ? q2 : r2;
    h[3] = lo ? q3 : r3;
    h[4] = lo ? l0 : q0;
    h[5] = lo ? l1 : q1;
    h[6] = lo ? l2 : q2;
}

__global__ __launch_bounds__(256, 2) void gru_fused_kernel(
    const float* __restrict__ x,     // [B, T, IN]
    const float* __restrict__ W_ih,  // [21, 5]
    const float* __restrict__ W_hh,  // [21, 7]
    const float* __restrict__ b_ih,  // [21]
    const float* __restrict__ b_hh,  // [21]
    const float* __restrict__ W_h0,  // [7, 1]
    const float* __restrict__ W_m,   // [3, 7]
    const float* __restrict__ b_m,   // [3]
    const float* __restrict__ W_r,   // [1, 7]
    const float* __restrict__ b_r,   // [1]
    float* __restrict__ out)
{
    __shared__ float lds_x[2][BPB * XSTR];   // 2 x 10.25 KB

    const int tid  = threadIdx.x;
    const int l    = tid & 15;           // lane within batch group
    const int j    = l & 7;              // hidden-unit slot (7 = pad)
    const int g    = tid >> 4;           // batch slot in block (0..15)
    const int b    = blockIdx.x * BPB + g;
    const int jj   = (j < 7) ? j : 6;    // clamp pad lane's weight loads
    const bool lo  = ((tid & 4) == 0);   // low quad of my 8-lane group
    const bool lo8 = ((l & 8) == 0);     // low half of my 16-lane group

    // ---- per-lane weight rows ----
    // slot0: r_j row (low half) / z_j row (high half); slot1: n_j row (both)
    const int row0 = lo8 ? jj : (Hn + jj);
    const int row1 = 2 * Hn + jj;

    float whh0[Hn], whh1[Hn];
    #pragma unroll
    for (int k = 0; k < Hn; ++k) {
        whh0[k] = W_hh[row0 * Hn + k];
        whh1[k] = W_hh[row1 * Hn + k];
    }
    float wih0[INn], wih1[INn];
    #pragma unroll
    for (int i = 0; i < INn; ++i) {
        wih0[i] = W_ih[row0 * INn + i];
        wih1[i] = W_ih[row1 * INn + i];
    }
    const float bh0 = b_hh[row0], bh1 = b_hh[row1];
    const float bi0 = b_ih[row0], bi1 = b_ih[row1];

    // head weights: lanes 0..2 -> W_m rows, lane 3 -> W_r, others zero
    float whead[Hn];
    float bhead = 0.0f;
    #pragma unroll
    for (int k = 0; k < Hn; ++k) whead[k] = 0.0f;
    if (l < 3) {
        #pragma unroll
        for (int k = 0; k < Hn; ++k) whead[k] = W_m[l * Hn + k];
        bhead = b_m[l];
    } else if (l == 3) {
        #pragma unroll
        for (int k = 0; k < Hn; ++k) whead[k] = W_r[k];
        bhead = b_r[0];
    }

    // ---- replicated hidden state (+ own value) ----
    float h[Hn];
    #pragma unroll
    for (int k = 0; k < Hn; ++k) h[k] = W_h0[k];
    float hj = W_h0[jj];

    const float* xb  = x + (long long)b * (Tn * INn);
    float* om  = out + (long long)b * (Tn * 3);
    float* orr = out + OFF_OR + (long long)b * Tn;

    // ---- prologue: stage tile 0 ----
    // per batch-tile: 160 floats = 80 float2; lane l takes float2 #(l + 16i)
    float2 stage[5];
    #pragma unroll
    for (int i = 0; i < 5; ++i)
        stage[i] = *(const float2*)(xb + 2 * (l + 16 * i));

    int cur = 0;
    for (int tl = 0; tl < NTILE; ++tl) {
        // commit staged tile to LDS
        #pragma unroll
        for (int i = 0; i < 5; ++i)
            *(float2*)&lds_x[cur][g * XSTR + 2 * (l + 16 * i)] = stage[i];
        __syncthreads();

        // prefetch next tile from global (consumed in 32 steps -> hidden)
        if (tl + 1 < NTILE) {
            const float* src = xb + (tl + 1) * (TILE * INn);
            #pragma unroll
            for (int i = 0; i < 5; ++i)
                stage[i] = *(const float2*)(src + 2 * (l + 16 * i));
        }

        const float* xl = &lds_x[cur][g * XSTR];

        // prime step-0 x from LDS
        float xc[INn];
        #pragma unroll
        for (int i = 0; i < INn; ++i) xc[i] = xl[i];

        #pragma unroll 4
        for (int tt = 0; tt < TILE; ++tt) {
            const int t = tl * TILE + tt;

            // prefetch next step's x from LDS (clamped; tt=31 re-reads self)
            const int tn = (tt + 1 < TILE) ? (tt + 1) : tt;
            float xnx[INn];
            #pragma unroll
            for (int i = 0; i < INn; ++i) xnx[i] = xl[tn * INn + i];

            // two matvecs on replicated h (slot0 = r/z row, slot1 = n row)
            float g0 = bh0, g1 = bh1;
            #pragma unroll
            for (int k = 0; k < Hn; ++k) {
                g0 = fmaf(whh0[k], h[k], g0);
                g1 = fmaf(whh1[k], h[k], g1);
            }
            // input projections
            float p0 = bi0, p1 = bi1;
            #pragma unroll
            for (int i = 0; i < INn; ++i) {
                p0 = fmaf(wih0[i], xc[i], p0);
                p1 = fmaf(wih1[i], xc[i], p1);
            }
            // slot0 gate: r (low half) / z (high half)
            float s = fast_sigmoid(g0 + p0);
            // exchange halves: low gets z, high gets r
            float sv = dppf<0x128>(s);            // row_ror:8
            float r_val = lo8 ? s : sv;
            float z_val = lo8 ? sv : s;
            // n gate (valid on ALL lanes: both halves hold real n-row weights)
            float n = fast_tanh(fmaf(r_val, g1, p1));
            float hnew = n + z_val * (hj - n);    // (1-z)*n + z*h
            hj = hnew;                            // own next-state (no gather dep)

            // replicate h across lanes (VALU DPP, verified R3 pattern)
            gather_h(hnew, lo, h);

            // heads (lane-private weights; only lanes 0..3 store)
            float acc = bhead;
            #pragma unroll
            for (int k = 0; k < Hn; ++k) acc = fmaf(whead[k], h[k], acc);
            if (l < 3) {
                om[t * 3 + l] = acc;
            } else if (l == 3) {
                orr[t] = acc;
            }

            #pragma unroll
            for (int i = 0; i < INn; ++i) xc[i] = xnx[i];
        }
        cur ^= 1;
    }

    // h_last: [1, B, H] (low half writes)
    if (l < Hn) out[OFF_HL + (long long)b * Hn + l] = h[l];
}

extern "C" void kernel_launch(void* const* d_in, const int* in_sizes, int n_in,
                              void* d_out, int out_size, void* d_ws, size_t ws_size,
                              hipStream_t stream) {
    const float* x    = (const float*)d_in[0];
    // d_in[1] = batch_size (scalar), unused — B compiled in
    const float* W_ih = (const float*)d_in[2];
    const float* W_hh = (const float*)d_in[3];
    const float* b_ih = (const float*)d_in[4];
    const float* b_hh = (const float*)d_in[5];
    const float* W_h0 = (const float*)d_in[6];
    const float* W_m  = (const float*)d_in[7];
    const float* b_m  = (const float*)d_in[8];
    const float* W_r  = (const float*)d_in[9];
    const float* b_r  = (const float*)d_in[10];
    float* out = (float*)d_out;

    dim3 grid(Bn / BPB);  // 512 blocks
    dim3 block(256);      // 16 batch elements x 16 lanes
    gru_fused_kernel<<<grid, block, 0, stream>>>(x, W_ih, W_hh, b_ih, b_hh,
                                                 W_h0, W_m, b_m, W_r, b_r, out);
}

// Round 5
// 241.067 us; speedup vs baseline: 1.5201x; 1.1494x over previous
//
#include <hip/hip_runtime.h>

// GRU: B=8192 chains, T=512 steps, IN=5, H=7, fused heads.
// R5: systolic row_ror:1 rotation fuses {h-replication, hidden matvec, head
// dot} into 7 DPP + packed v_pk_fma_f32 streams. R4 post-mortem: issue-bound
// (VALUBusy 76%), 18-op gather + scalar FMAs were the waste. Per lane-step:
// 8 pk_fma hidden (r|z,n packed), 5 pk_fma proj, 8 fma head (deferred 1 step,
// rides the same rotation), 4 transcendentals. 16 lanes/batch, 2 waves/SIMD.
// DPP direction anchor (R3/R4 passed): row_shr:N dst[n]=src[n-N];
// row_ror:N dst[n]=src[(n-N)mod16]. After i ror:1 steps lane l holds
// hnew(unit (l-i)&7); weight index k=(j-i)&7, k==7 -> weight 0 (pad killed).

namespace {
constexpr int Bn = 8192;
constexpr int Tn = 512;
constexpr int INn = 5;
constexpr int Hn = 7;
constexpr int TILE = 32;
constexpr int NTILE = Tn / TILE;         // 16
constexpr int BPB = 16;                  // batches per block (256 thr / 16)
constexpr int XSTR = 164;                // padded floats/batch in LDS
constexpr long long OFF_OR = (long long)Bn * Tn * 3;
constexpr long long OFF_HL = OFF_OR + (long long)Bn * Tn;
constexpr float LOG2E = 1.44269504088896340736f;
}

typedef float v2f __attribute__((ext_vector_type(2)));

__device__ __forceinline__ v2f pk_fma(v2f a, v2f b, v2f c) {
    return __builtin_elementwise_fma(a, b, c);
}
__device__ __forceinline__ v2f splat2(float x) { return (v2f){x, x}; }

__device__ __forceinline__ float fast_sigmoid(float x) {
    float e = __builtin_amdgcn_exp2f(-LOG2E * x);
    return __builtin_amdgcn_rcpf(1.0f + e);
}
__device__ __forceinline__ float fast_tanh(float x) {
    float e = __builtin_amdgcn_exp2f(-2.0f * LOG2E * x);
    return __builtin_amdgcn_rcpf(1.0f + e) * 2.0f - 1.0f;
}

template<int CTRL>
__device__ __forceinline__ float dppf(float v) {
    int r = __builtin_amdgcn_update_dpp(0, __builtin_bit_cast(int, v),
                                        CTRL, 0xF, 0xF, true);
    return __builtin_bit_cast(float, r);
}

__global__ __launch_bounds__(256, 2) void gru_fused_kernel(
    const float* __restrict__ x,     // [B, T, IN]
    const float* __restrict__ W_ih,  // [21, 5]
    const float* __restrict__ W_hh,  // [21, 7]
    const float* __restrict__ b_ih,  // [21]
    const float* __restrict__ b_hh,  // [21]
    const float* __restrict__ W_h0,  // [7, 1]
    const float* __restrict__ W_m,   // [3, 7]
    const float* __restrict__ b_m,   // [3]
    const float* __restrict__ W_r,   // [1, 7]
    const float* __restrict__ b_r,   // [1]
    float* __restrict__ out)
{
    __shared__ float lds_x[2][BPB * XSTR];   // 2 x 10.25 KB

    const int tid  = threadIdx.x;
    const int l    = tid & 15;           // lane within 16-lane batch group
    const int j    = l & 7;              // hidden-unit slot (7 = pad, clones 6)
    const int g    = tid >> 4;           // batch slot in block
    const int b    = blockIdx.x * BPB + g;
    const int jj   = (j < 7) ? j : 6;
    const bool lo8 = ((l & 8) == 0);
    const bool l4  = (l < 4);

    // ---- rotated, packed weights ----
    // slot0 = r row (low half) / z row (high half); slot1 = n row (both)
    const int row0 = lo8 ? jj : (Hn + jj);
    const int row1 = 2 * Hn + jj;

    v2f whh_rot[8];
    float whd_rot[8];
    #pragma unroll
    for (int i = 0; i < 8; ++i) {
        const int k = (j - i) & 7;
        if (k < 7) {
            whh_rot[i] = (v2f){W_hh[row0 * Hn + k], W_hh[row1 * Hn + k]};
            whd_rot[i] = (l < 3) ? W_m[l * Hn + k]
                       : (l == 3) ? W_r[k] : 0.0f;
        } else {
            whh_rot[i] = (v2f){0.0f, 0.0f};
            whd_rot[i] = 0.0f;
        }
    }
    v2f wih01[INn];
    #pragma unroll
    for (int i = 0; i < INn; ++i)
        wih01[i] = (v2f){W_ih[row0 * INn + i], W_ih[row1 * INn + i]};
    const v2f biasH = (v2f){b_hh[row0], b_hh[row1]};
    const v2f biasP = (v2f){b_ih[row0], b_ih[row1]};
    const float bhead = (l < 3) ? b_m[l] : (l == 3) ? b_r[0] : 0.0f;

    // ---- state: own hidden value only (replication fused into rotation) ----
    float hj = W_h0[jj];

    const float* xb = x + (long long)b * (Tn * INn);
    float* om  = out + (long long)b * (Tn * 3);
    float* orr = out + OFF_OR + (long long)b * Tn;

    // deferred-head store pointer: at global step s we store head(h_s) to
    // index s-1 (skipped at s=0); epilogue stores head(h_T) at index T-1.
    float* hp = (l < 3) ? (om + l - 3) : (orr - 1);
    const int hstride = (l < 3) ? 3 : 1;

    // ---- prologue: stage tile 0 (160 floats = 80 float2 per batch) ----
    float2 stage[5];
    #pragma unroll
    for (int i = 0; i < 5; ++i)
        stage[i] = *(const float2*)(xb + 2 * (l + 16 * i));

    int cur = 0;
    for (int tl = 0; tl < NTILE; ++tl) {
        #pragma unroll
        for (int i = 0; i < 5; ++i)
            *(float2*)&lds_x[cur][g * XSTR + 2 * (l + 16 * i)] = stage[i];
        __syncthreads();

        if (tl + 1 < NTILE) {
            const float* src = xb + (tl + 1) * (TILE * INn);
            #pragma unroll
            for (int i = 0; i < 5; ++i)
                stage[i] = *(const float2*)(src + 2 * (l + 16 * i));
        }

        const float* xl = &lds_x[cur][g * XSTR];

        float xc[INn];
        #pragma unroll
        for (int i = 0; i < INn; ++i) xc[i] = xl[i];

        #pragma unroll 4
        for (int tt = 0; tt < TILE; ++tt) {
            const int sg = tl * TILE + tt;      // global step

            // prefetch next step's x (clamped)
            const int tn = (tt + 1 < TILE) ? (tt + 1) : tt;
            float xnx[INn];
            #pragma unroll
            for (int i = 0; i < INn; ++i) xnx[i] = xl[tn * INn + i];

            // systolic rotation: hidden matvec (packed) + head dot share it
            v2f accA = biasH;
            v2f accB = (v2f){0.0f, 0.0f};
            float hd = bhead;
            float hr = hj;                       // i=0: own value
            accA = pk_fma(whh_rot[0], splat2(hr), accA);
            hd = fmaf(whd_rot[0], hr, hd);
            #pragma unroll
            for (int i = 1; i < 8; ++i) {
                hr = dppf<0x121>(hr);            // row_ror:1
                if (i & 1) accB = pk_fma(whh_rot[i], splat2(hr), accB);
                else       accA = pk_fma(whh_rot[i], splat2(hr), accA);
                hd = fmaf(whd_rot[i], hr, hd);
            }
            v2f accH = accA + accB;              // (g0, g1) hidden-only

            // input projection (kept separate: r multiplies hidden part only)
            v2f accP = biasP;
            #pragma unroll
            for (int i = 0; i < INn; ++i)
                accP = pk_fma(wih01[i], splat2(xc[i]), accP);

            // store deferred head(h_sg) at index sg-1
            if (sg > 0 && l4) *hp = hd;
            hp += hstride;

            // gates
            float s  = fast_sigmoid(accH[0] + accP[0]);
            float sv = dppf<0x128>(s);           // row_ror:8 half-swap
            float r_val = lo8 ? s : sv;
            float z_val = lo8 ? sv : s;
            float n = fast_tanh(fmaf(r_val, accH[1], accP[1]));
            hj = n + z_val * (hj - n);           // (1-z)*n + z*h

            #pragma unroll
            for (int i = 0; i < INn; ++i) xc[i] = xnx[i];
        }
        cur ^= 1;
    }

    // epilogue: head of final h (one more rotation), stored at index T-1
    {
        float hd = bhead;
        float hr = hj;
        hd = fmaf(whd_rot[0], hr, hd);
        #pragma unroll
        for (int i = 1; i < 8; ++i) {
            hr = dppf<0x121>(hr);
            hd = fmaf(whd_rot[i], hr, hd);
        }
        if (l4) *hp = hd;
    }

    // h_last: [1, B, H]
    if (l < Hn) out[OFF_HL + (long long)b * Hn + l] = hj;
}

extern "C" void kernel_launch(void* const* d_in, const int* in_sizes, int n_in,
                              void* d_out, int out_size, void* d_ws, size_t ws_size,
                              hipStream_t stream) {
    const float* x    = (const float*)d_in[0];
    // d_in[1] = batch_size (scalar), unused — B compiled in
    const float* W_ih = (const float*)d_in[2];
    const float* W_hh = (const float*)d_in[3];
    const float* b_ih = (const float*)d_in[4];
    const float* b_hh = (const float*)d_in[5];
    const float* W_h0 = (const float*)d_in[6];
    const float* W_m  = (const float*)d_in[7];
    const float* b_m  = (const float*)d_in[8];
    const float* W_r  = (const float*)d_in[9];
    const float* b_r  = (const float*)d_in[10];
    float* out = (float*)d_out;

    dim3 grid(Bn / BPB);  // 512 blocks
    dim3 block(256);      // 16 batch elements x 16 lanes
    gru_fused_kernel<<<grid, block, 0, stream>>>(x, W_ih, W_hh, b_ih, b_hh,
                                                 W_h0, W_m, b_m, W_r, b_r, out);
}

// Round 6
// 234.233 us; speedup vs baseline: 1.5644x; 1.0292x over previous
//
#include <hip/hip_runtime.h>

// GRU: B=8192 chains, T=512 steps, IN=5, H=7, fused heads.
// R6 (from R5 @135us, VALUBusy 68%): (1) independent row_ror:i (i=1..7)
// replaces the serial ror:1 chain -> rotation chain depth 7->1, same count;
// (2) x read as 4-step 20-float chunks via ds_read_b128, register
// double-buffered -> ~10 instrs/step of ds_read_b32+copies become ~1.25;
// (3) head-store guard folded to the tt==0 unroll instance only.
// Layout (R4/R5, verified): 16 lanes/batch, lane l: slot0 = r row (l<8) /
// z row (l>=8), slot1 = n row (both halves); one sigmoid/lane + ror:8 swap;
// heads deferred 1 step, riding the same rotation. 2 waves/SIMD.
// DPP anchor (R3-R5 passed): row_ror:N dst[n]=src[(n-N)mod16]; position i
// holds unit (l-i)&7; weight k=(j-i)&7, k==7 -> 0 (pad killed).

namespace {
constexpr int Bn = 8192;
constexpr int Tn = 512;
constexpr int INn = 5;
constexpr int Hn = 7;
constexpr int TILE = 32;
constexpr int NTILE = Tn / TILE;         // 16
constexpr int BPB = 16;                  // batches per block (256 thr / 16)
constexpr int XSTR = 164;                // padded floats/batch in LDS
                                         // (g*164+w)%32 = (4g+w)%32: the 4
                                         // groups of a wave occupy disjoint
                                         // 4-dword bank ranges per b128
constexpr long long OFF_OR = (long long)Bn * Tn * 3;
constexpr long long OFF_HL = OFF_OR + (long long)Bn * Tn;
constexpr float LOG2E = 1.44269504088896340736f;
}

typedef float v2f __attribute__((ext_vector_type(2)));

__device__ __forceinline__ v2f pk_fma(v2f a, v2f b, v2f c) {
    return __builtin_elementwise_fma(a, b, c);
}
__device__ __forceinline__ v2f splat2(float x) { return (v2f){x, x}; }

__device__ __forceinline__ float fast_sigmoid(float x) {
    float e = __builtin_amdgcn_exp2f(-LOG2E * x);
    return __builtin_amdgcn_rcpf(1.0f + e);
}
__device__ __forceinline__ float fast_tanh(float x) {
    float e = __builtin_amdgcn_exp2f(-2.0f * LOG2E * x);
    return __builtin_amdgcn_rcpf(1.0f + e) * 2.0f - 1.0f;
}

template<int CTRL>
__device__ __forceinline__ float dppf(float v) {
    int r = __builtin_amdgcn_update_dpp(0, __builtin_bit_cast(int, v),
                                        CTRL, 0xF, 0xF, true);
    return __builtin_bit_cast(float, r);
}

__global__ __launch_bounds__(256, 2) void gru_fused_kernel(
    const float* __restrict__ x,     // [B, T, IN]
    const float* __restrict__ W_ih,  // [21, 5]
    const float* __restrict__ W_hh,  // [21, 7]
    const float* __restrict__ b_ih,  // [21]
    const float* __restrict__ b_hh,  // [21]
    const float* __restrict__ W_h0,  // [7, 1]
    const float* __restrict__ W_m,   // [3, 7]
    const float* __restrict__ b_m,   // [3]
    const float* __restrict__ W_r,   // [1, 7]
    const float* __restrict__ b_r,   // [1]
    float* __restrict__ out)
{
    __shared__ float lds_x[2][BPB * XSTR];   // 2 x 10.25 KB

    const int tid  = threadIdx.x;
    const int l    = tid & 15;           // lane within 16-lane batch group
    const int j    = l & 7;              // hidden-unit slot (7 = pad, clones 6)
    const int g    = tid >> 4;           // batch slot in block
    const int b    = blockIdx.x * BPB + g;
    const int jj   = (j < 7) ? j : 6;
    const bool lo8 = ((l & 8) == 0);
    const bool l4  = (l < 4);

    // ---- rotated, packed weights ----
    const int row0 = lo8 ? jj : (Hn + jj);   // r row (lo) / z row (hi)
    const int row1 = 2 * Hn + jj;            // n row (both halves)

    v2f whh_rot[8];
    float whd_rot[8];
    #pragma unroll
    for (int i = 0; i < 8; ++i) {
        const int k = (j - i) & 7;
        if (k < 7) {
            whh_rot[i] = (v2f){W_hh[row0 * Hn + k], W_hh[row1 * Hn + k]};
            whd_rot[i] = (l < 3) ? W_m[l * Hn + k]
                       : (l == 3) ? W_r[k] : 0.0f;
        } else {
            whh_rot[i] = (v2f){0.0f, 0.0f};
            whd_rot[i] = 0.0f;
        }
    }
    v2f wih01[INn];
    #pragma unroll
    for (int i = 0; i < INn; ++i)
        wih01[i] = (v2f){W_ih[row0 * INn + i], W_ih[row1 * INn + i]};
    const v2f biasH = (v2f){b_hh[row0], b_hh[row1]};
    const v2f biasP = (v2f){b_ih[row0], b_ih[row1]};
    const float bhead = (l < 3) ? b_m[l] : (l == 3) ? b_r[0] : 0.0f;

    float hj = W_h0[jj];

    const float* xb = x + (long long)b * (Tn * INn);
    float* om  = out + (long long)b * (Tn * 3);
    float* orr = out + OFF_OR + (long long)b * Tn;

    // deferred-head store pointer: at step s store head(h_s) to index s-1
    float* hp = (l < 3) ? (om + l - 3) : (orr - 1);
    const int hstride = (l < 3) ? 3 : 1;

    // ---- prologue: stage tile 0 (160 floats = 80 float2 per batch) ----
    float2 stage[5];
    #pragma unroll
    for (int i = 0; i < 5; ++i)
        stage[i] = *(const float2*)(xb + 2 * (l + 16 * i));

    int cur = 0;
    for (int tl = 0; tl < NTILE; ++tl) {
        #pragma unroll
        for (int i = 0; i < 5; ++i)
            *(float2*)&lds_x[cur][g * XSTR + 2 * (l + 16 * i)] = stage[i];
        __syncthreads();

        if (tl + 1 < NTILE) {
            const float* src = xb + (tl + 1) * (TILE * INn);
            #pragma unroll
            for (int i = 0; i < 5; ++i)
                stage[i] = *(const float2*)(src + 2 * (l + 16 * i));
        }

        // x for this tile as 8 chunks of 4 steps (20 floats = 5 float4),
        // register double-buffered: chunk c+1 loads issue while c computes.
        const float4* xq = (const float4*)&lds_x[cur][g * XSTR];
        float4 xbuf[2][5];
        #pragma unroll
        for (int k = 0; k < 5; ++k) xbuf[0][k] = xq[k];

        #pragma unroll
        for (int c = 0; c < 8; ++c) {
            if (c < 7) {
                #pragma unroll
                for (int k = 0; k < 5; ++k)
                    xbuf[(c + 1) & 1][k] = xq[(c + 1) * 5 + k];
            }
            const float* xcf = (const float*)xbuf[c & 1];

            #pragma unroll
            for (int ss = 0; ss < 4; ++ss) {
                const int tt = c * 4 + ss;

                // systolic rotation, all rors independent off hj:
                // hidden matvec (packed r|z,n) + head dot share it
                v2f accA = biasH;
                v2f accB = (v2f){0.0f, 0.0f};
                float hd = bhead;
                accA = pk_fma(whh_rot[0], splat2(hj), accA);
                hd = fmaf(whd_rot[0], hj, hd);
                {
                    float h1 = dppf<0x121>(hj);
                    accB = pk_fma(whh_rot[1], splat2(h1), accB);
                    hd = fmaf(whd_rot[1], h1, hd);
                    float h2 = dppf<0x122>(hj);
                    accA = pk_fma(whh_rot[2], splat2(h2), accA);
                    hd = fmaf(whd_rot[2], h2, hd);
                    float h3 = dppf<0x123>(hj);
                    accB = pk_fma(whh_rot[3], splat2(h3), accB);
                    hd = fmaf(whd_rot[3], h3, hd);
                    float h4 = dppf<0x124>(hj);
                    accA = pk_fma(whh_rot[4], splat2(h4), accA);
                    hd = fmaf(whd_rot[4], h4, hd);
                    float h5 = dppf<0x125>(hj);
                    accB = pk_fma(whh_rot[5], splat2(h5), accB);
                    hd = fmaf(whd_rot[5], h5, hd);
                    float h6 = dppf<0x126>(hj);
                    accA = pk_fma(whh_rot[6], splat2(h6), accA);
                    hd = fmaf(whd_rot[6], h6, hd);
                    float h7 = dppf<0x127>(hj);
                    accB = pk_fma(whh_rot[7], splat2(h7), accB);
                    hd = fmaf(whd_rot[7], h7, hd);
                }
                v2f accH = accA + accB;          // (g0, g1) hidden-only

                // input projection (r multiplies hidden part only)
                v2f accP = biasP;
                #pragma unroll
                for (int i = 0; i < INn; ++i)
                    accP = pk_fma(wih01[i], splat2(xcf[5 * ss + i]), accP);

                // deferred head(h_t) -> index t-1 (guard folds away for tt>0)
                if ((tl > 0 || tt > 0) && l4) *hp = hd;
                hp += hstride;

                // gates
                float s  = fast_sigmoid(accH[0] + accP[0]);
                float sv = dppf<0x128>(s);       // row_ror:8 half-swap
                float r_val = lo8 ? s : sv;
                float z_val = lo8 ? sv : s;
                float n = fast_tanh(fmaf(r_val, accH[1], accP[1]));
                hj = n + z_val * (hj - n);       // (1-z)*n + z*h
            }
        }
        cur ^= 1;
    }

    // epilogue: head of final h (one more rotation), stored at index T-1
    {
        float hd = bhead;
        hd = fmaf(whd_rot[0], hj, hd);
        hd = fmaf(whd_rot[1], dppf<0x121>(hj), hd);
        hd = fmaf(whd_rot[2], dppf<0x122>(hj), hd);
        hd = fmaf(whd_rot[3], dppf<0x123>(hj), hd);
        hd = fmaf(whd_rot[4], dppf<0x124>(hj), hd);
        hd = fmaf(whd_rot[5], dppf<0x125>(hj), hd);
        hd = fmaf(whd_rot[6], dppf<0x126>(hj), hd);
        hd = fmaf(whd_rot[7], dppf<0x127>(hj), hd);
        if (l4) *hp = hd;
    }

    // h_last: [1, B, H]
    if (l < Hn) out[OFF_HL + (long long)b * Hn + l] = hj;
}

extern "C" void kernel_launch(void* const* d_in, const int* in_sizes, int n_in,
                              void* d_out, int out_size, void* d_ws, size_t ws_size,
                              hipStream_t stream) {
    const float* x    = (const float*)d_in[0];
    // d_in[1] = batch_size (scalar), unused — B compiled in
    const float* W_ih = (const float*)d_in[2];
    const float* W_hh = (const float*)d_in[3];
    const float* b_ih = (const float*)d_in[4];
    const float* b_hh = (const float*)d_in[5];
    const float* W_h0 = (const float*)d_in[6];
    const float* W_m  = (const float*)d_in[7];
    const float* b_m  = (const float*)d_in[8];
    const float* W_r  = (const float*)d_in[9];
    const float* b_r  = (const float*)d_in[10];
    float* out = (float*)d_out;

    dim3 grid(Bn / BPB);  // 512 blocks
    dim3 block(256);      // 16 batch elements x 16 lanes
    gru_fused_kernel<<<grid, block, 0, stream>>>(x, W_ih, W_hh, b_ih, b_hh,
                                                 W_h0, W_m, b_m, W_r, b_r, out);
}